// Round 13
// baseline (950.509 us; speedup 1.0000x reference)
//
#include <hip/hip_runtime.h>

#define NI 8
#define NH 64
#define NO 8
#define NB 256
#define NT 2048

typedef float v2f __attribute__((ext_vector_type(2)));

__device__ __forceinline__ v2f fma2(v2f a, v2f b, v2f c) {
    return __builtin_elementwise_fma(a, b, c);
}

// tanh(s) = 1 - 2/(exp(2s)+1); safe at +-inf
__device__ __forceinline__ float tanh_fast(float s) {
    float e = __expf(2.0f * s);
    return fmaf(-2.0f, __builtin_amdgcn_rcpf(e + 1.0f), 1.0f);
}

// broadcast lane k's value to all lanes (VALU pipe, no LDS)
__device__ __forceinline__ float rlane(float v, int k) {
    return __int_as_float(__builtin_amdgcn_readlane(__float_as_int(v), k));
}

// R12 structure (4 waves, one per SIMD, busy-spin flags) with ONE change:
// wave D no longer touches global memory in its steady loop. R12's D issued
// an x prefetch load with 1 iteration of slack + a store sharing vmcnt every
// step -> D stalls on s_waitcnt vmcnt(N) at L2/HBM latency (~200-900cyc);
// A needs vfu>=t+7 so D's period caps the whole conveyor (955cyc/step
// observed vs ~500 for A's VALU work; A idle ~680cyc/step).
// D now holds x chunks in registers (lane j = timestep c*64+j), u-dot via
// 8 readlane + 8 fma; next chunk loaded 63 iters ahead; the only vmcnt wait
// is once per 64 steps. A, B, C byte-identical to R12.
__attribute__((amdgpu_waves_per_eu(1, 1)))
__global__ void __launch_bounds__(256) rnn_quad2(
    const float* __restrict__ x,
    const float* __restrict__ W_ih0, const float* __restrict__ W_hh0,
    const float* __restrict__ b_ih0, const float* __restrict__ b_hh0,
    const float* __restrict__ W_ih1, const float* __restrict__ W_hh1,
    const float* __restrict__ b_ih1, const float* __restrict__ b_hh1,
    const float* __restrict__ W_fc,  const float* __restrict__ b_fc,
    float* __restrict__ out)
{
    const int b    = blockIdx.x;
    const int tid  = threadIdx.x;
    const int wid  = tid >> 6;
    const int lane = tid & 63;
    const int o    = lane & 7;
    const int kg   = lane >> 3;

    __shared__ float h0r[16][NH];   // A -> B ring
    __shared__ float pir[16][NH];   // B -> C ring
    __shared__ float h1r[16][NH];   // C -> D ring
    __shared__ float ur[32][NH];    // D -> A ring (u = Wih0@x + bias0)
    __shared__ int   fa, fb, fc, fd, fu;

    if (tid == 0) { fa = -1; fb = -1; fc = -1; fd = -1; fu = -1; }
    __syncthreads();

    volatile int* vfa = &fa;
    volatile int* vfb = &fb;
    volatile int* vfc = &fc;
    volatile int* vfd = &fd;
    volatile int* vfu = &fu;

    const float*  xb   = x   + (size_t)b * NT * NI;
    float*        outb = out + (size_t)b * NT * NO;
    const size_t  hid  = (size_t)NB * NT * NO;

    if (wid == 0) {
        // ================= wave A: layer-0 chain (VALU gather) =================
        float w[NH];
        #pragma unroll
        for (int k = 0; k < NH; ++k) w[k] = W_hh0[lane * NH + k];
        float h0n = 0.0f;

        for (int t = 0; t < NT; ++t) {
            if ((t & 7) == 0) {
                const int needU = (t + 7 < NT) ? t + 7 : NT - 1;
                while (*vfu < needU) {}            // u availability (D ~13 ahead)
                while (*vfb < t - 9) {}            // h0r slot reuse vs B
                asm volatile("" ::: "memory");
            }
            const float uv = ur[t & 31][lane];     // ds_read; hidden under dot

            float c0 = 0.f, c1 = 0.f, c2 = 0.f, c3 = 0.f;
            #pragma unroll
            for (int k = 0; k < NH; k += 8) {
                const float s0 = rlane(h0n, k + 0), s1 = rlane(h0n, k + 1);
                const float s2 = rlane(h0n, k + 2), s3 = rlane(h0n, k + 3);
                const float s4 = rlane(h0n, k + 4), s5 = rlane(h0n, k + 5);
                const float s6 = rlane(h0n, k + 6), s7 = rlane(h0n, k + 7);
                c0 = fmaf(s0, w[k + 0], c0); c1 = fmaf(s1, w[k + 1], c1);
                c2 = fmaf(s2, w[k + 2], c2); c3 = fmaf(s3, w[k + 3], c3);
                c0 = fmaf(s4, w[k + 4], c0); c1 = fmaf(s5, w[k + 5], c1);
                c2 = fmaf(s6, w[k + 6], c2); c3 = fmaf(s7, w[k + 7], c3);
            }
            h0n = tanh_fast(((c0 + c1) + (c2 + c3)) + uv);

            h0r[t & 15][lane] = h0n;
            asm volatile("s_waitcnt lgkmcnt(0)" ::: "memory");
            *vfa = t;                              // publish every step
        }
        out[hid + (size_t)b * NH + lane] = h0n;                     // h0 final
    } else if (wid == 1) {
        // ================= wave B: pi producer (LDS gather) =================
        v2f w2[NH / 2];
        #pragma unroll
        for (int k = 0; k < NH / 2; ++k)
            w2[k] = v2f{W_ih1[lane * NH + 2 * k], W_ih1[lane * NH + 2 * k + 1]};

        for (int t = 0; t < NT; ++t) {
            while (*vfa < t) {}                    // h0[t] available
            if ((t & 7) == 0) {
                while (*vfc < t - 9) {}            // pir slot reuse vs C
            }
            asm volatile("" ::: "memory");

            const float4* hp = (const float4*)(&h0r[t & 15][0]);
            v2f a0 = {0.f, 0.f}, a1 = {0.f, 0.f}, a2 = {0.f, 0.f}, a3 = {0.f, 0.f};
            #pragma unroll
            for (int k = 0; k < 16; ++k) {
                const float4 g = hp[k];
                const v2f lo = {g.x, g.y}, hi = {g.z, g.w};
                if (k & 1) { a2 = fma2(lo, w2[2 * k], a2); a3 = fma2(hi, w2[2 * k + 1], a3); }
                else       { a0 = fma2(lo, w2[2 * k], a0); a1 = fma2(hi, w2[2 * k + 1], a1); }
            }
            const v2f sv = (a0 + a1) + (a2 + a3);
            pir[t & 15][lane] = sv.x + sv.y;
            asm volatile("s_waitcnt lgkmcnt(0)" ::: "memory");
            *vfb = t;                              // publish every step
        }
    } else if (wid == 2) {
        // ================= wave C: layer-1 chain (VALU gather) =================
        float w[NH];
        #pragma unroll
        for (int k = 0; k < NH; ++k) w[k] = W_hh1[lane * NH + k];
        const float bias1 = b_ih1[lane] + b_hh1[lane];
        float h1n = 0.0f;

        for (int t = 0; t < NT; ++t) {
            while (*vfb < t) {}                    // pi[t] available
            if ((t & 7) == 0) {
                while (*vfd < t - 9) {}            // h1r slot reuse vs D
            }
            asm volatile("" ::: "memory");
            const float pv = pir[t & 15][lane];    // ds_read; hidden under dot

            float c0 = bias1, c1 = 0.f, c2 = 0.f, c3 = 0.f;
            #pragma unroll
            for (int k = 0; k < NH; k += 8) {
                const float s0 = rlane(h1n, k + 0), s1 = rlane(h1n, k + 1);
                const float s2 = rlane(h1n, k + 2), s3 = rlane(h1n, k + 3);
                const float s4 = rlane(h1n, k + 4), s5 = rlane(h1n, k + 5);
                const float s6 = rlane(h1n, k + 6), s7 = rlane(h1n, k + 7);
                c0 = fmaf(s0, w[k + 0], c0); c1 = fmaf(s1, w[k + 1], c1);
                c2 = fmaf(s2, w[k + 2], c2); c3 = fmaf(s3, w[k + 3], c3);
                c0 = fmaf(s4, w[k + 4], c0); c1 = fmaf(s5, w[k + 5], c1);
                c2 = fmaf(s6, w[k + 6], c2); c3 = fmaf(s7, w[k + 7], c3);
            }
            h1n = tanh_fast(((c0 + c1) + (c2 + c3)) + pv);

            h1r[t & 15][lane] = h1n;
            asm volatile("s_waitcnt lgkmcnt(0)" ::: "memory");
            *vfc = t;                              // publish every step
        }
        out[hid + (size_t)NB * NH + (size_t)b * NH + lane] = h1n;   // h1 final
    } else {
        // ====== wave D: u producer (reg-chunked x, no steady-state global loads)
        // ====== + FC + store ======
        float wih0r[NI];
        #pragma unroll
        for (int i = 0; i < NI; ++i) wih0r[i] = W_ih0[lane * NI + i];
        const float bias0 = b_ih0[lane] + b_hh0[lane];
        float wfcr[8];
        #pragma unroll
        for (int m = 0; m < 8; ++m) wfcr[m] = W_fc[o * NH + kg * 8 + m];
        const float bfc = b_fc[o];

        // chunk registers: lane j holds x[c*64 + j][0..8)
        float4 xc0 = *(const float4*)(xb + (size_t)lane * NI);
        float4 xc1 = *(const float4*)(xb + (size_t)lane * NI + 4);

        // prologue: u[0..15] from chunk 0
        for (int s = 0; s < 16; ++s) {
            float u = bias0;
            u = fmaf(rlane(xc0.x, s), wih0r[0], u);
            u = fmaf(rlane(xc0.y, s), wih0r[1], u);
            u = fmaf(rlane(xc0.z, s), wih0r[2], u);
            u = fmaf(rlane(xc0.w, s), wih0r[3], u);
            u = fmaf(rlane(xc1.x, s), wih0r[4], u);
            u = fmaf(rlane(xc1.y, s), wih0r[5], u);
            u = fmaf(rlane(xc1.z, s), wih0r[6], u);
            u = fmaf(rlane(xc1.w, s), wih0r[7], u);
            ur[s][lane] = u;
        }
        asm volatile("s_waitcnt lgkmcnt(0)" ::: "memory");
        *vfu = 15;

        // chunk 1 in flight (used at t==48, ~48 periods away)
        float4 xn0 = *(const float4*)(xb + (size_t)(64 + lane) * NI);
        float4 xn1 = *(const float4*)(xb + (size_t)(64 + lane) * NI + 4);

        for (int t = 0; t < NT; ++t) {
            const int s = t + 16;
            if (s < NT) {
                const int m = t & 63;
                if (m == 48) { xc0 = xn0; xc1 = xn1; }   // s enters chunk (t>>6)+1
                if (m == 49) {                            // load chunk after next
                    const int cn = (s >> 6) + 1;          // used 63 iters from now
                    if (cn < NT / 64) {
                        xn0 = *(const float4*)(xb + (size_t)(cn * 64 + lane) * NI);
                        xn1 = *(const float4*)(xb + (size_t)(cn * 64 + lane) * NI + 4);
                    }
                }
                const int j2 = s & 63;
                float u = bias0;
                u = fmaf(rlane(xc0.x, j2), wih0r[0], u);
                u = fmaf(rlane(xc0.y, j2), wih0r[1], u);
                u = fmaf(rlane(xc0.z, j2), wih0r[2], u);
                u = fmaf(rlane(xc0.w, j2), wih0r[3], u);
                u = fmaf(rlane(xc1.x, j2), wih0r[4], u);
                u = fmaf(rlane(xc1.y, j2), wih0r[5], u);
                u = fmaf(rlane(xc1.z, j2), wih0r[6], u);
                u = fmaf(rlane(xc1.w, j2), wih0r[7], u);
                ur[s & 31][lane] = u;
            }
            if ((t & 3) == 3) {                    // publish u progress
                asm volatile("s_waitcnt lgkmcnt(0)" ::: "memory");
                *vfu = (s < NT) ? s : NT - 1;
            }

            while (*vfc < t) {}                    // h1[t] available
            asm volatile("" ::: "memory");
            const float4 u0 = *(const float4*)(&h1r[t & 15][kg * 8]);
            const float4 u1 = *(const float4*)(&h1r[t & 15][kg * 8 + 4]);
            float p = u0.x * wfcr[0] + u0.y * wfcr[1] + u0.z * wfcr[2] + u0.w * wfcr[3]
                    + u1.x * wfcr[4] + u1.y * wfcr[5] + u1.z * wfcr[6] + u1.w * wfcr[7];
            p += __shfl_xor(p, 8);
            p += __shfl_xor(p, 16);
            p += __shfl_xor(p, 32);
            if (lane < NO) outb[(size_t)t * NO + o] = p + bfc;   // fire-and-forget

            if ((t & 3) == 3) {                    // h1r consumption progress
                asm volatile("s_waitcnt lgkmcnt(0)" ::: "memory");
                *vfd = t;
            }
        }
    }
}

extern "C" void kernel_launch(void* const* d_in, const int* in_sizes, int n_in,
                              void* d_out, int out_size, void* d_ws, size_t ws_size,
                              hipStream_t stream) {
    const float* x     = (const float*)d_in[0];
    const float* W_ih0 = (const float*)d_in[1];
    const float* W_hh0 = (const float*)d_in[2];
    const float* b_ih0 = (const float*)d_in[3];
    const float* b_hh0 = (const float*)d_in[4];
    const float* W_ih1 = (const float*)d_in[5];
    const float* W_hh1 = (const float*)d_in[6];
    const float* b_ih1 = (const float*)d_in[7];
    const float* b_hh1 = (const float*)d_in[8];
    const float* W_fc  = (const float*)d_in[9];
    const float* b_fc  = (const float*)d_in[10];

    rnn_quad2<<<dim3(NB), dim3(256), 0, stream>>>(
        x, W_ih0, W_hh0, b_ih0, b_hh0,
        W_ih1, W_hh1, b_ih1, b_hh1, W_fc, b_fc,
        (float*)d_out);
}

// Round 14
// 722.224 us; speedup vs baseline: 1.3161x; 1.3161x over previous
//
#include <hip/hip_runtime.h>

#define NI 8
#define NH 64
#define NO 8
#define NB 256
#define NT 2048

typedef float v2f __attribute__((ext_vector_type(2)));

__device__ __forceinline__ v2f fma2(v2f a, v2f b, v2f c) {
    return __builtin_elementwise_fma(a, b, c);
}

// tanh(s) = 1 - 2/(exp(2s)+1); safe at +-inf
__device__ __forceinline__ float tanh_fast(float s) {
    float e = __expf(2.0f * s);
    return fmaf(-2.0f, __builtin_amdgcn_rcpf(e + 1.0f), 1.0f);
}

// 3 waves, one block per batch element, zero barriers, TWO flag hops.
// R13 lesson: the 4-wave conveyor's per-step cost was dominated by publish
// (ds_write+lgkmcnt+flag) + poll on EVERY hop (x4). Merge to minimize hops:
//   A: h0[t]=tanh(Whh0@h0[t-1]+u[t]); SAME gather feeds Wih1 dot -> pi[t-1]
//      (16 b128 bcast reads + 64 pk_fma for both dots)
//   C: h1[t]=tanh(pi[t]+b1+Whh1@h1[t-1]); SAME gather gives each lane the
//      COMPLETE FC(t-1) dot for output lane&7 (no reduction!) + store
//   D: u[t]=Wih0@x[t]+bias0 (tiny; x broadcast loads 1-step ahead)
// A publishes fa gran-2; C batch-polls gran-4, publishes fc2 gran-4;
// D publishes fu gran-4, polls fa gran-8.
__attribute__((amdgpu_waves_per_eu(1, 1)))
__global__ void __launch_bounds__(192) rnn_tri3(
    const float* __restrict__ x,
    const float* __restrict__ W_ih0, const float* __restrict__ W_hh0,
    const float* __restrict__ b_ih0, const float* __restrict__ b_hh0,
    const float* __restrict__ W_ih1, const float* __restrict__ W_hh1,
    const float* __restrict__ b_ih1, const float* __restrict__ b_hh1,
    const float* __restrict__ W_fc,  const float* __restrict__ b_fc,
    float* __restrict__ out)
{
    const int b    = blockIdx.x;
    const int tid  = threadIdx.x;
    const int wid  = tid >> 6;
    const int lane = tid & 63;

    __shared__ float ur[32][NH];    // D -> A: u = Wih0@x + bias0
    __shared__ float pir[16][NH];   // A -> C: Wih1@h0[t]
    __shared__ float h0s[NH];       // A-private gather buffer
    __shared__ float h1s[NH];       // C-private gather buffer
    __shared__ int   fa, fc2, fu;

    if (tid == 0) { fa = -1; fc2 = -1; fu = -1; }
    __syncthreads();

    volatile int* vfa  = &fa;
    volatile int* vfc2 = &fc2;
    volatile int* vfu  = &fu;

    const float*  xb   = x   + (size_t)b * NT * NI;
    float*        outb = out + (size_t)b * NT * NO;
    const size_t  hid  = (size_t)NB * NT * NO;

    if (wid == 0) {
        // ========== wave A: h0 chain + pi production (one gather, two dots) ==========
        v2f wh[NH / 2], wi[NH / 2];
        #pragma unroll
        for (int k = 0; k < NH / 2; ++k) {
            wh[k] = v2f{W_hh0[lane * NH + 2 * k], W_hh0[lane * NH + 2 * k + 1]};
            wi[k] = v2f{W_ih1[lane * NH + 2 * k], W_ih1[lane * NH + 2 * k + 1]};
        }
        float h0n = 0.0f;

        for (int t = 0; t < NT; ++t) {
            if ((t & 7) == 0) {
                const int needU = (t + 7 < NT) ? t + 7 : NT - 1;
                while (*vfu < needU) {}          // u availability (D leads ~16)
                while (*vfc2 < t - 11) {}        // pir slot reuse vs C
                asm volatile("" ::: "memory");
            }
            const float uv = ur[t & 31][lane];   // issued early, used after dots

            h0s[lane] = h0n;                     // h0[t-1]; in-wave write->read order
            const float4* hp = (const float4*)h0s;
            v2f aW0 = {0,0}, aW1 = {0,0}, aW2 = {0,0}, aW3 = {0,0};
            v2f aI0 = {0,0}, aI1 = {0,0}, aI2 = {0,0}, aI3 = {0,0};
            #pragma unroll
            for (int k = 0; k < 16; ++k) {
                const float4 g = hp[k];
                const v2f lo = {g.x, g.y}, hi = {g.z, g.w};
                if (k & 1) {
                    aW2 = fma2(lo, wh[2 * k], aW2); aW3 = fma2(hi, wh[2 * k + 1], aW3);
                    aI2 = fma2(lo, wi[2 * k], aI2); aI3 = fma2(hi, wi[2 * k + 1], aI3);
                } else {
                    aW0 = fma2(lo, wh[2 * k], aW0); aW1 = fma2(hi, wh[2 * k + 1], aW1);
                    aI0 = fma2(lo, wi[2 * k], aI0); aI1 = fma2(hi, wi[2 * k + 1], aI1);
                }
            }
            const v2f sW = (aW0 + aW1) + (aW2 + aW3);
            const v2f sI = (aI0 + aI1) + (aI2 + aI3);
            const float dW = sW.x + sW.y;        // Whh0 @ h0[t-1]
            const float dI = sI.x + sI.y;        // Wih1 @ h0[t-1] = pi[t-1]

            if (t > 0) pir[(t - 1) & 15][lane] = dI;
            if (t & 1) {                         // publish gran 2
                asm volatile("s_waitcnt lgkmcnt(0)" ::: "memory");
                *vfa = t - 1;
            }
            h0n = tanh_fast(dW + uv);            // u contains bias0
        }

        // epilogue: pi[NT-1] from h0[NT-1]
        while (*vfc2 < NT - 17) {}               // last pir slot reuse
        asm volatile("" ::: "memory");
        h0s[lane] = h0n;
        {
            const float4* hp = (const float4*)h0s;
            v2f aI0 = {0,0}, aI1 = {0,0}, aI2 = {0,0}, aI3 = {0,0};
            #pragma unroll
            for (int k = 0; k < 16; ++k) {
                const float4 g = hp[k];
                const v2f lo = {g.x, g.y}, hi = {g.z, g.w};
                if (k & 1) { aI2 = fma2(lo, wi[2 * k], aI2); aI3 = fma2(hi, wi[2 * k + 1], aI3); }
                else       { aI0 = fma2(lo, wi[2 * k], aI0); aI1 = fma2(hi, wi[2 * k + 1], aI1); }
            }
            const v2f sI = (aI0 + aI1) + (aI2 + aI3);
            pir[(NT - 1) & 15][lane] = sI.x + sI.y;
        }
        asm volatile("s_waitcnt lgkmcnt(0)" ::: "memory");
        *vfa = NT - 1;
        out[hid + (size_t)b * NH + lane] = h0n;                     // h0 final
    } else if (wid == 1) {
        // ========== wave C: h1 chain + FC (one gather, two dots) ==========
        v2f wh1[NH / 2], wf[NH / 2];
        const int o = lane & 7;
        #pragma unroll
        for (int k = 0; k < NH / 2; ++k) {
            wh1[k] = v2f{W_hh1[lane * NH + 2 * k], W_hh1[lane * NH + 2 * k + 1]};
            wf[k]  = v2f{W_fc[o * NH + 2 * k],     W_fc[o * NH + 2 * k + 1]};
        }
        const float bias1 = b_ih1[lane] + b_hh1[lane];
        const float bfc   = b_fc[o];
        float h1n = 0.0f;

        for (int t = 0; t < NT; ++t) {
            if ((t & 3) == 0) {                  // batch-poll: pi[t..t+3]
                const int need = (t + 3 < NT) ? t + 3 : NT - 1;
                while (*vfa < need) {}
                asm volatile("" ::: "memory");
            }
            const float pv = pir[t & 15][lane];  // issued early

            h1s[lane] = h1n;                     // h1[t-1]
            const float4* hp = (const float4*)h1s;
            v2f aW0 = {0,0}, aW1 = {0,0}, aW2 = {0,0}, aW3 = {0,0};
            v2f aF0 = {0,0}, aF1 = {0,0}, aF2 = {0,0}, aF3 = {0,0};
            #pragma unroll
            for (int k = 0; k < 16; ++k) {
                const float4 g = hp[k];
                const v2f lo = {g.x, g.y}, hi = {g.z, g.w};
                if (k & 1) {
                    aW2 = fma2(lo, wh1[2 * k], aW2); aW3 = fma2(hi, wh1[2 * k + 1], aW3);
                    aF2 = fma2(lo, wf[2 * k],  aF2); aF3 = fma2(hi, wf[2 * k + 1],  aF3);
                } else {
                    aW0 = fma2(lo, wh1[2 * k], aW0); aW1 = fma2(hi, wh1[2 * k + 1], aW1);
                    aF0 = fma2(lo, wf[2 * k],  aF0); aF1 = fma2(hi, wf[2 * k + 1],  aF1);
                }
            }
            const v2f sW = (aW0 + aW1) + (aW2 + aW3);
            const v2f sF = (aF0 + aF1) + (aF2 + aF3);
            const float dW = sW.x + sW.y;        // Whh1 @ h1[t-1]
            const float dF = sF.x + sF.y;        // FC(t-1), complete per lane

            if (t > 0 && lane < NO)
                outb[(size_t)(t - 1) * NO + o] = dF + bfc;   // fire-and-forget

            h1n = tanh_fast(dW + pv + bias1);
            if ((t & 3) == 3) {                  // consumption progress gran 4
                asm volatile("s_waitcnt lgkmcnt(0)" ::: "memory");
                *vfc2 = t;
            }
        }

        // epilogue: FC(NT-1)
        h1s[lane] = h1n;
        {
            const float4* hp = (const float4*)h1s;
            v2f aF0 = {0,0}, aF1 = {0,0}, aF2 = {0,0}, aF3 = {0,0};
            #pragma unroll
            for (int k = 0; k < 16; ++k) {
                const float4 g = hp[k];
                const v2f lo = {g.x, g.y}, hi = {g.z, g.w};
                if (k & 1) { aF2 = fma2(lo, wf[2 * k], aF2); aF3 = fma2(hi, wf[2 * k + 1], aF3); }
                else       { aF0 = fma2(lo, wf[2 * k], aF0); aF1 = fma2(hi, wf[2 * k + 1], aF1); }
            }
            const v2f sF = (aF0 + aF1) + (aF2 + aF3);
            if (lane < NO) outb[(size_t)(NT - 1) * NO + o] = sF.x + sF.y + bfc;
        }
        out[hid + (size_t)NB * NH + (size_t)b * NH + lane] = h1n;   // h1 final
    } else if (wid == 2) {
        // ========== wave D: u producer only ==========
        float wih0r[NI];
        #pragma unroll
        for (int i = 0; i < NI; ++i) wih0r[i] = W_ih0[lane * NI + i];
        const float bias0 = b_ih0[lane] + b_hh0[lane];

        // prologue: u[0..15]
        for (int s = 0; s < 16; ++s) {
            const float4 xa = *(const float4*)(xb + (size_t)s * NI);
            const float4 xc = *(const float4*)(xb + (size_t)s * NI + 4);
            float u = bias0;
            u = fmaf(xa.x, wih0r[0], u); u = fmaf(xa.y, wih0r[1], u);
            u = fmaf(xa.z, wih0r[2], u); u = fmaf(xa.w, wih0r[3], u);
            u = fmaf(xc.x, wih0r[4], u); u = fmaf(xc.y, wih0r[5], u);
            u = fmaf(xc.z, wih0r[6], u); u = fmaf(xc.w, wih0r[7], u);
            ur[s][lane] = u;
        }
        asm volatile("s_waitcnt lgkmcnt(0)" ::: "memory");
        *vfu = 15;

        float4 px0 = {0,0,0,0}, px1 = {0,0,0,0};
        if (16 < NT) {
            px0 = *(const float4*)(xb + (size_t)16 * NI);
            px1 = *(const float4*)(xb + (size_t)16 * NI + 4);
        }

        for (int t = 0; t < NT; ++t) {
            if ((t & 7) == 0) {                  // ur slot reuse vs A
                while (*vfa < t - 8) {}
                asm volatile("" ::: "memory");
            }
            const int s = t + 16;
            if (s < NT) {
                float u = bias0;
                u = fmaf(px0.x, wih0r[0], u); u = fmaf(px0.y, wih0r[1], u);
                u = fmaf(px0.z, wih0r[2], u); u = fmaf(px0.w, wih0r[3], u);
                u = fmaf(px1.x, wih0r[4], u); u = fmaf(px1.y, wih0r[5], u);
                u = fmaf(px1.z, wih0r[6], u); u = fmaf(px1.w, wih0r[7], u);
                ur[s & 31][lane] = u;
                if (s + 1 < NT) {                // next x, 1 period of slack
                    px0 = *(const float4*)(xb + (size_t)(s + 1) * NI);
                    px1 = *(const float4*)(xb + (size_t)(s + 1) * NI + 4);
                }
            }
            if ((t & 3) == 3) {                  // publish gran 4
                asm volatile("s_waitcnt lgkmcnt(0)" ::: "memory");
                *vfu = (s < NT) ? s : NT - 1;
            }
        }
    }
}

extern "C" void kernel_launch(void* const* d_in, const int* in_sizes, int n_in,
                              void* d_out, int out_size, void* d_ws, size_t ws_size,
                              hipStream_t stream) {
    const float* x     = (const float*)d_in[0];
    const float* W_ih0 = (const float*)d_in[1];
    const float* W_hh0 = (const float*)d_in[2];
    const float* b_ih0 = (const float*)d_in[3];
    const float* b_hh0 = (const float*)d_in[4];
    const float* W_ih1 = (const float*)d_in[5];
    const float* W_hh1 = (const float*)d_in[6];
    const float* b_ih1 = (const float*)d_in[7];
    const float* b_hh1 = (const float*)d_in[8];
    const float* W_fc  = (const float*)d_in[9];
    const float* b_fc  = (const float*)d_in[10];

    rnn_tri3<<<dim3(NB), dim3(192), 0, stream>>>(
        x, W_ih0, W_hh0, b_ih0, b_hh0,
        W_ih1, W_hh1, b_ih1, b_hh1, W_fc, b_fc,
        (float*)d_out);
}

// Round 15
// 709.500 us; speedup vs baseline: 1.3397x; 1.0179x over previous
//
#include <hip/hip_runtime.h>

#define NI 8
#define NH 64
#define NO 8
#define NB 256
#define NT 2048

typedef float v2f __attribute__((ext_vector_type(2)));

__device__ __forceinline__ v2f fma2(v2f a, v2f b, v2f c) {
    return __builtin_elementwise_fma(a, b, c);
}

// tanh(s) = 1 - 2/(exp(2s)+1); safe at +-inf
__device__ __forceinline__ float tanh_fast(float s) {
    float e = __expf(2.0f * s);
    return fmaf(-2.0f, __builtin_amdgcn_rcpf(e + 1.0f), 1.0f);
}

// R14 3-wave merged conveyor + exposed-latency fixes:
//  1. ring reads (uv/pv) prefetched one step ahead into registers
//  2. D: 8-step windows, 2-window load lookahead (global latency off the fuse)
//  3. A: pir write deferred to next step's top -> publish lgkmcnt(0) ~free
//  4. pir ring 32-deep (reuse margin 2 -> 20 steps vs C's gran-4 publish)
//   A: h0[t]=tanh(Whh0@h0[t-1]+u[t]); same gather -> Wih1 dot = pi[t-1]
//   C: h1[t]=tanh(pi[t]+b1+Whh1@h1[t-1]); same gather -> complete FC(t-1)/lane
//   D: u[t]=Wih0@x[t]+b0 in 8-step windows
__attribute__((amdgpu_waves_per_eu(1, 1)))
__global__ void __launch_bounds__(192) rnn_tri4(
    const float* __restrict__ x,
    const float* __restrict__ W_ih0, const float* __restrict__ W_hh0,
    const float* __restrict__ b_ih0, const float* __restrict__ b_hh0,
    const float* __restrict__ W_ih1, const float* __restrict__ W_hh1,
    const float* __restrict__ b_ih1, const float* __restrict__ b_hh1,
    const float* __restrict__ W_fc,  const float* __restrict__ b_fc,
    float* __restrict__ out)
{
    const int b    = blockIdx.x;
    const int tid  = threadIdx.x;
    const int wid  = tid >> 6;
    const int lane = tid & 63;

    __shared__ __align__(16) float ur[32][NH];    // D -> A ring
    __shared__ __align__(16) float pir[32][NH];   // A -> C ring
    __shared__ __align__(16) float h0s[NH];       // A-private gather buffer
    __shared__ __align__(16) float h1s[NH];       // C-private gather buffer
    __shared__ int fa, fc2, fu;

    if (tid == 0) { fa = -1; fc2 = -1; fu = -1; }
    __syncthreads();

    volatile int* vfa  = &fa;
    volatile int* vfc2 = &fc2;
    volatile int* vfu  = &fu;

    const float*  xb   = x   + (size_t)b * NT * NI;
    float*        outb = out + (size_t)b * NT * NO;
    const size_t  hid  = (size_t)NB * NT * NO;

    if (wid == 0) {
        // ========== wave A: h0 chain + pi production ==========
        v2f wh[NH / 2], wi[NH / 2];
        #pragma unroll
        for (int k = 0; k < NH / 2; ++k) {
            wh[k] = v2f{W_hh0[lane * NH + 2 * k], W_hh0[lane * NH + 2 * k + 1]};
            wi[k] = v2f{W_ih1[lane * NH + 2 * k], W_ih1[lane * NH + 2 * k + 1]};
        }
        float h0n = 0.0f, dI_prev = 0.0f;

        while (*vfu < 7) {}                      // u[0] ready (D's first window)
        asm volatile("" ::: "memory");
        float uv_next = ur[0][lane];

        for (int t = 0; t < NT; ++t) {
            if ((t & 7) == 0) {
                const int needU = (t + 8 < NT) ? t + 8 : NT - 1;
                while (*vfu < needU) {}          // u availability (covers prefetch)
                while (*vfc2 < t - 27) {}        // pir slot reuse vs C (32-ring)
                asm volatile("" ::: "memory");
            }
            h0s[lane] = h0n;                     // h0[t-1]
            const float4* hp = (const float4*)h0s;
            float4 gv[16];
            #pragma unroll
            for (int k = 0; k < 16; ++k) gv[k] = hp[k];      // issue gather
            if (t >= 2) pir[(t - 2) & 31][lane] = dI_prev;   // deferred pi write
            const float uv_cur = uv_next;
            uv_next = ur[(t + 1) & 31][lane];                // prefetch u[t+1]

            v2f aW0 = {0,0}, aW1 = {0,0}, aW2 = {0,0}, aW3 = {0,0};
            v2f aI0 = {0,0}, aI1 = {0,0}, aI2 = {0,0}, aI3 = {0,0};
            #pragma unroll
            for (int k = 0; k < 16; ++k) {
                const v2f lo = {gv[k].x, gv[k].y}, hi = {gv[k].z, gv[k].w};
                if (k & 1) {
                    aW2 = fma2(lo, wh[2 * k], aW2); aW3 = fma2(hi, wh[2 * k + 1], aW3);
                    aI2 = fma2(lo, wi[2 * k], aI2); aI3 = fma2(hi, wi[2 * k + 1], aI3);
                } else {
                    aW0 = fma2(lo, wh[2 * k], aW0); aW1 = fma2(hi, wh[2 * k + 1], aW1);
                    aI0 = fma2(lo, wi[2 * k], aI0); aI1 = fma2(hi, wi[2 * k + 1], aI1);
                }
            }
            if (t & 1) {                         // publish: all DS long returned
                asm volatile("s_waitcnt lgkmcnt(0)" ::: "memory");
                *vfa = t - 2;
            }
            const v2f sW = (aW0 + aW1) + (aW2 + aW3);
            const v2f sI = (aI0 + aI1) + (aI2 + aI3);
            dI_prev = sI.x + sI.y;               // pi[t-1], written next step
            h0n = tanh_fast(sW.x + sW.y + uv_cur);
        }

        // epilogue: pi[NT-2] (pending) and pi[NT-1] (fresh gather)
        while (*vfc2 < NT - 33) {}
        asm volatile("" ::: "memory");
        pir[(NT - 2) & 31][lane] = dI_prev;
        h0s[lane] = h0n;
        {
            const float4* hp = (const float4*)h0s;
            v2f aI0 = {0,0}, aI1 = {0,0}, aI2 = {0,0}, aI3 = {0,0};
            #pragma unroll
            for (int k = 0; k < 16; ++k) {
                const float4 g = hp[k];
                const v2f lo = {g.x, g.y}, hi = {g.z, g.w};
                if (k & 1) { aI2 = fma2(lo, wi[2 * k], aI2); aI3 = fma2(hi, wi[2 * k + 1], aI3); }
                else       { aI0 = fma2(lo, wi[2 * k], aI0); aI1 = fma2(hi, wi[2 * k + 1], aI1); }
            }
            const v2f sI = (aI0 + aI1) + (aI2 + aI3);
            pir[(NT - 1) & 31][lane] = sI.x + sI.y;
        }
        asm volatile("s_waitcnt lgkmcnt(0)" ::: "memory");
        *vfa = NT - 1;
        out[hid + (size_t)b * NH + lane] = h0n;                     // h0 final
    } else if (wid == 1) {
        // ========== wave C: h1 chain + FC ==========
        const int o = lane & 7;
        v2f wh1[NH / 2], wf[NH / 2];
        #pragma unroll
        for (int k = 0; k < NH / 2; ++k) {
            wh1[k] = v2f{W_hh1[lane * NH + 2 * k], W_hh1[lane * NH + 2 * k + 1]};
            wf[k]  = v2f{W_fc[o * NH + 2 * k],     W_fc[o * NH + 2 * k + 1]};
        }
        const float bias1 = b_ih1[lane] + b_hh1[lane];
        const float bfc   = b_fc[o];
        float h1n = 0.0f;

        while (*vfa < 1) {}                      // pi[0] ready
        asm volatile("" ::: "memory");
        float pv_next = pir[0][lane];

        for (int t = 0; t < NT; ++t) {
            if ((t & 3) == 0) {                  // covers prefetch through t+4
                const int need = (t + 4 < NT) ? t + 4 : NT - 1;
                while (*vfa < need) {}
                asm volatile("" ::: "memory");
            }
            h1s[lane] = h1n;                     // h1[t-1]
            const float4* hp = (const float4*)h1s;
            float4 gv[16];
            #pragma unroll
            for (int k = 0; k < 16; ++k) gv[k] = hp[k];
            const float pv_cur = pv_next;
            pv_next = pir[(t + 1) & 31][lane];   // prefetch pi[t+1]

            // on-chain dot first: Whh1 @ h1[t-1]
            v2f aW0 = {0,0}, aW1 = {0,0}, aW2 = {0,0}, aW3 = {0,0};
            #pragma unroll
            for (int k = 0; k < 16; ++k) {
                const v2f lo = {gv[k].x, gv[k].y}, hi = {gv[k].z, gv[k].w};
                if (k & 1) { aW2 = fma2(lo, wh1[2 * k], aW2); aW3 = fma2(hi, wh1[2 * k + 1], aW3); }
                else       { aW0 = fma2(lo, wh1[2 * k], aW0); aW1 = fma2(hi, wh1[2 * k + 1], aW1); }
            }
            const v2f sW = (aW0 + aW1) + (aW2 + aW3);
            h1n = tanh_fast(sW.x + sW.y + pv_cur + bias1);

            // off-chain: FC(t-1) from the same gather (complete dot per lane)
            v2f aF0 = {0,0}, aF1 = {0,0}, aF2 = {0,0}, aF3 = {0,0};
            #pragma unroll
            for (int k = 0; k < 16; ++k) {
                const v2f lo = {gv[k].x, gv[k].y}, hi = {gv[k].z, gv[k].w};
                if (k & 1) { aF2 = fma2(lo, wf[2 * k], aF2); aF3 = fma2(hi, wf[2 * k + 1], aF3); }
                else       { aF0 = fma2(lo, wf[2 * k], aF0); aF1 = fma2(hi, wf[2 * k + 1], aF1); }
            }
            const v2f sF = (aF0 + aF1) + (aF2 + aF3);
            if (t > 0 && lane < NO)
                outb[(size_t)(t - 1) * NO + o] = sF.x + sF.y + bfc;  // fire-and-forget

            if ((t & 3) == 3) {                  // consumption progress
                asm volatile("s_waitcnt lgkmcnt(0)" ::: "memory");
                *vfc2 = t;
            }
        }

        // epilogue: FC(NT-1)
        h1s[lane] = h1n;
        {
            const float4* hp = (const float4*)h1s;
            v2f aF0 = {0,0}, aF1 = {0,0}, aF2 = {0,0}, aF3 = {0,0};
            #pragma unroll
            for (int k = 0; k < 16; ++k) {
                const float4 g = hp[k];
                const v2f lo = {g.x, g.y}, hi = {g.z, g.w};
                if (k & 1) { aF2 = fma2(lo, wf[2 * k], aF2); aF3 = fma2(hi, wf[2 * k + 1], aF3); }
                else       { aF0 = fma2(lo, wf[2 * k], aF0); aF1 = fma2(hi, wf[2 * k + 1], aF1); }
            }
            const v2f sF = (aF0 + aF1) + (aF2 + aF3);
            if (lane < NO) outb[(size_t)(NT - 1) * NO + o] = sF.x + sF.y + bfc;
        }
        out[hid + (size_t)NB * NH + (size_t)b * NH + lane] = h1n;   // h1 final
    } else if (wid == 2) {
        // ========== wave D: u producer, 8-step windows, 2-window lookahead ==========
        float wih0r[NI];
        #pragma unroll
        for (int i = 0; i < NI; ++i) wih0r[i] = W_ih0[lane * NI + i];
        const float bias0 = b_ih0[lane] + b_hh0[lane];

        float4 xc[16], xn[16];                   // xc = window w, xn = window w+1
        #pragma unroll
        for (int j = 0; j < 8; ++j) {
            xc[2 * j]     = *(const float4*)(xb + (size_t)j * NI);
            xc[2 * j + 1] = *(const float4*)(xb + (size_t)j * NI + 4);
        }
        #pragma unroll
        for (int j = 0; j < 8; ++j) {
            xn[2 * j]     = *(const float4*)(xb + (size_t)(8 + j) * NI);
            xn[2 * j + 1] = *(const float4*)(xb + (size_t)(8 + j) * NI + 4);
        }

        for (int w = 0; w < NT / 8; ++w) {
            while (*vfa < 8 * w - 20) {}         // ur slot reuse vs A (margin 14)
            asm volatile("" ::: "memory");
            #pragma unroll
            for (int j = 0; j < 8; ++j) {
                float u = bias0;
                u = fmaf(xc[2 * j].x,     wih0r[0], u);
                u = fmaf(xc[2 * j].y,     wih0r[1], u);
                u = fmaf(xc[2 * j].z,     wih0r[2], u);
                u = fmaf(xc[2 * j].w,     wih0r[3], u);
                u = fmaf(xc[2 * j + 1].x, wih0r[4], u);
                u = fmaf(xc[2 * j + 1].y, wih0r[5], u);
                u = fmaf(xc[2 * j + 1].z, wih0r[6], u);
                u = fmaf(xc[2 * j + 1].w, wih0r[7], u);
                ur[(8 * w + j) & 31][lane] = u;
            }
            asm volatile("s_waitcnt lgkmcnt(0)" ::: "memory");
            *vfu = 8 * w + 7;
            #pragma unroll
            for (int j = 0; j < 16; ++j) xc[j] = xn[j];      // rotate windows
            if (w + 2 < NT / 8) {                // load window w+2 (used in 2 windows)
                const size_t base = (size_t)(w + 2) * 8;
                #pragma unroll
                for (int j = 0; j < 8; ++j) {
                    xn[2 * j]     = *(const float4*)(xb + (base + j) * NI);
                    xn[2 * j + 1] = *(const float4*)(xb + (base + j) * NI + 4);
                }
            }
        }
    }
}

extern "C" void kernel_launch(void* const* d_in, const int* in_sizes, int n_in,
                              void* d_out, int out_size, void* d_ws, size_t ws_size,
                              hipStream_t stream) {
    const float* x     = (const float*)d_in[0];
    const float* W_ih0 = (const float*)d_in[1];
    const float* W_hh0 = (const float*)d_in[2];
    const float* b_ih0 = (const float*)d_in[3];
    const float* b_hh0 = (const float*)d_in[4];
    const float* W_ih1 = (const float*)d_in[5];
    const float* W_hh1 = (const float*)d_in[6];
    const float* b_ih1 = (const float*)d_in[7];
    const float* b_hh1 = (const float*)d_in[8];
    const float* W_fc  = (const float*)d_in[9];
    const float* b_fc  = (const float*)d_in[10];

    rnn_tri4<<<dim3(NB), dim3(192), 0, stream>>>(
        x, W_ih0, W_hh0, b_ih0, b_hh0,
        W_ih1, W_hh1, b_ih1, b_hh1, W_fc, b_fc,
        (float*)d_out);
}